// Round 4
// baseline (400.581 us; speedup 1.0000x reference)
//
#include <hip/hip_runtime.h>

#define B_ROWS 65536
#define F_FEAT 39
#define V_VOC  100000
#define D_PAD  640
#define BN_EPS 1e-5f

typedef __bf16 bf16x8 __attribute__((ext_vector_type(8)));
typedef float  f32x16 __attribute__((ext_vector_type(16)));

__device__ __forceinline__ unsigned short toBF(float x) {
  unsigned int u = __float_as_uint(x);
  u += 0x7fffu + ((u >> 16) & 1u);
  return (unsigned short)(u >> 16);
}

// ---------------- K1: gather fm2, write Xt (bf16, transposed, padded), fs = first + FM2 ------
// 16 rows/block, 16 lanes/row (4B/lane gathers). LDS ~25.9 KB -> 6 blocks/CU (24 waves/CU),
// vs R3's 32-row/8-lane version (51.7 KB, 3 blocks/CU, 12 waves/CU) which ran at 2 TB/s.
// Also zeroes M (640x640 floats, 100 per block x 4096 blocks).
__global__ __launch_bounds__(256) void k1_gather(
    const int* __restrict__ Xi, const float* __restrict__ Xv,
    const float* __restrict__ emb1, const float* __restrict__ emb2,
    unsigned short* __restrict__ XT, float* __restrict__ fs,
    float* __restrict__ Mz) {
  if (threadIdx.x < 100)
    Mz[(size_t)blockIdx.x * 100 + threadIdx.x] = 0.f;

  const int b0 = blockIdx.x * 16;
  __shared__ int            sIdx[16][40];
  __shared__ float          sXv[16][40];
  __shared__ unsigned short xt[16][648];   // 648-short stride: +4 bank shift per row

  for (int u = threadIdx.x; u < 16 * 39; u += 256) {
    int r = u / 39, f = u - r * 39;
    sIdx[r][f] = Xi[(size_t)(b0 + r) * 39 + f];
    sXv[r][f]  = Xv[(size_t)(b0 + r) * 39 + f];
  }
  __syncthreads();

  const int r = threadIdx.x >> 4, ec = threadIdx.x & 15;  // one float component per lane
  float sv = 0.f, ss = 0.f;
#pragma unroll 4
  for (int f = 0; f < 39; ++f) {
    int id = sIdx[r][f];
    float xv = sXv[r][f];
    float a = emb2[((size_t)f * V_VOC + id) * 16 + ec] * xv;
    sv += a; ss += a * a;
    xt[r][f * 16 + ec] = toBF(a);
  }
  // first-order term: lane ec handles f = ec, ec+16, ec+32 (exact fp32 emb1 gather)
  float fo = 0.f;
  for (int f = ec; f < 39; f += 16)
    fo += emb1[(size_t)f * V_VOC + sIdx[r][f]] * sXv[r][f];

  float q = 0.5f * (sv * sv - ss) + fo;
  q += __shfl_xor(q, 1);
  q += __shfl_xor(q, 2);
  q += __shfl_xor(q, 4);
  q += __shfl_xor(q, 8);
  if (ec == 0) fs[b0 + r] = q;
  __syncthreads();

  // write Xt[m][b0..b0+15]; m=624 -> ones column, 625..639 -> zeros
  for (int m = threadIdx.x; m < 640; m += 256) {
    unsigned short* dst = XT + (size_t)m * B_ROWS + b0;
    unsigned int q2[8];
    if (m < 624) {
#pragma unroll
      for (int rr = 0; rr < 8; ++rr)
        q2[rr] = (unsigned int)xt[2 * rr][m] | ((unsigned int)xt[2 * rr + 1][m] << 16);
    } else {
      unsigned int fill = (m == 624) ? 0x3f803f80u : 0u;
#pragma unroll
      for (int rr = 0; rr < 8; ++rr) q2[rr] = fill;
    }
    uint4 w0, w1;
    w0.x = q2[0]; w0.y = q2[1]; w0.z = q2[2]; w0.w = q2[3];
    w1.x = q2[4]; w1.y = q2[5]; w1.z = q2[6]; w1.w = q2[7];
    *reinterpret_cast<uint4*>(dst)     = w0;
    *reinterpret_cast<uint4*>(dst + 8) = w1;
  }
}

// ---------------- K2: M += Xt * Xt^T  (640x640, symmetric tiles ti<=tj), bf16 MFMA ----------
#define KSPLIT 32
__global__ __launch_bounds__(256) void k2_syrk(const unsigned short* __restrict__ XT,
                                               float* __restrict__ M) {
  const int ks = blockIdx.x & (KSPLIT - 1);
  int pair = blockIdx.x >> 5;
  int ti = 0, p = pair;
  while (p >= 5 - ti) { p -= 5 - ti; ++ti; }
  const int tj = ti + p;

  __shared__ unsigned short pa[128 * 64];
  __shared__ unsigned short pb[128 * 64];

  const int lane = threadIdx.x & 63, wid = threadIdx.x >> 6;
  const int wm = wid >> 1, wn = wid & 1;
  const int rl = lane & 31, hh = lane >> 5;

  f32x16 acc00, acc01, acc10, acc11;
#pragma unroll
  for (int i = 0; i < 16; ++i) { acc00[i] = 0.f; acc01[i] = 0.f; acc10[i] = 0.f; acc11[i] = 0.f; }

  const int krange = B_ROWS / KSPLIT;  // 2048
  const int kbase = ks * krange;

  for (int kt = 0; kt < krange; kt += 64) {
    const int k0 = kbase + kt;
#pragma unroll
    for (int g2 = 0; g2 < 4; ++g2) {
      const int g = threadIdx.x + g2 * 256;
      const int r = g >> 3, j = g & 7;
      uint4 va = *reinterpret_cast<const uint4*>(XT + (size_t)(ti * 128 + r) * B_ROWS + k0 + j * 8);
      *reinterpret_cast<uint4*>((char*)pa + r * 128 + ((j ^ (r & 7)) << 4)) = va;
      uint4 vb = *reinterpret_cast<const uint4*>(XT + (size_t)(tj * 128 + r) * B_ROWS + k0 + j * 8);
      *reinterpret_cast<uint4*>((char*)pb + r * 128 + ((j ^ (r & 7)) << 4)) = vb;
    }
    __syncthreads();
#pragma unroll
    for (int kc = 0; kc < 4; ++kc) {
      const int ra0 = wm * 64 + rl, ra1 = wm * 64 + 32 + rl;
      const int rb0 = wn * 64 + rl, rb1 = wn * 64 + 32 + rl;
      bf16x8 a0 = *reinterpret_cast<const bf16x8*>((char*)pa + ra0 * 128 + (((kc * 2 + hh) ^ (ra0 & 7)) << 4));
      bf16x8 a1 = *reinterpret_cast<const bf16x8*>((char*)pa + ra1 * 128 + (((kc * 2 + hh) ^ (ra1 & 7)) << 4));
      bf16x8 b0 = *reinterpret_cast<const bf16x8*>((char*)pb + rb0 * 128 + (((kc * 2 + hh) ^ (rb0 & 7)) << 4));
      bf16x8 b1 = *reinterpret_cast<const bf16x8*>((char*)pb + rb1 * 128 + (((kc * 2 + hh) ^ (rb1 & 7)) << 4));
      acc00 = __builtin_amdgcn_mfma_f32_32x32x16_bf16(a0, b0, acc00, 0, 0, 0);
      acc01 = __builtin_amdgcn_mfma_f32_32x32x16_bf16(a0, b1, acc01, 0, 0, 0);
      acc10 = __builtin_amdgcn_mfma_f32_32x32x16_bf16(a1, b0, acc10, 0, 0, 0);
      acc11 = __builtin_amdgcn_mfma_f32_32x32x16_bf16(a1, b1, acc11, 0, 0, 0);
    }
    __syncthreads();
  }

#pragma unroll
  for (int rr = 0; rr < 16; ++rr) {
    const int rloc = (rr & 3) + ((rr >> 2) << 3) + hh * 4;
    const int row0 = ti * 128 + wm * 64 + rloc;
    const int row1 = row0 + 32;
    const int col0 = tj * 128 + wn * 64 + rl;
    atomicAdd(&M[row0 * D_PAD + col0], acc00[rr]);
    atomicAdd(&M[row0 * D_PAD + col0 + 32], acc01[rr]);
    atomicAdd(&M[row1 * D_PAD + col0], acc10[rr]);
    atomicAdd(&M[row1 * D_PAD + col0 + 32], acc11[rr]);
  }
}

// ---------------- K3a: Cov + mu from M --------------------------------------------------------
__device__ __forceinline__ float fetchM(const float* M, int a, int b) {
  if ((a >> 7) > (b >> 7)) { int t = a; a = b; b = t; }
  return M[a * D_PAD + b];
}
__global__ void k3a_cov(const float* __restrict__ M, float* __restrict__ Cov,
                        float* __restrict__ mu) {
  const int i = blockIdx.x;
  const float inv = 1.f / 65536.f;
  const float mui = fetchM(M, 624, i) * inv;
  for (int j = threadIdx.x; j < D_PAD; j += 256) {
    float muj = fetchM(M, 624, j) * inv;
    Cov[i * D_PAD + j] = fetchM(M, i, j) * inv - mui * muj;
    if (i == 0) mu[j] = muj;
  }
}

// ---------------- qform: alpha[k] = g[k] * rsqrt( W[:,k]^T Cov W[:,k] + eps ), 2 k's/block -----
__global__ __launch_bounds__(256) void qform(const float* __restrict__ Cov,
                                             const float* __restrict__ W, const int ldw,
                                             const float* __restrict__ g,
                                             float* __restrict__ alpha) {
  const int k0 = blockIdx.x * 2;
  __shared__ float w0s[624], w1s[624];
  for (int i = threadIdx.x; i < 624; i += 256) {
    w0s[i] = W[(size_t)i * ldw + k0];
    w1s[i] = W[(size_t)i * ldw + k0 + 1];
  }
  __syncthreads();
  const int j0 = threadIdx.x, j1 = threadIdx.x + 256, j2 = threadIdx.x + 512;
  const bool v2 = (j2 < 624);
  const float wj00 = w0s[j0], wj01 = w0s[j1], wj02 = v2 ? w0s[j2] : 0.f;
  const float wj10 = w1s[j0], wj11 = w1s[j1], wj12 = v2 ? w1s[j2] : 0.f;
  float acc0 = 0.f, acc1 = 0.f;
  for (int i = 0; i < 624; ++i) {
    const float wi0 = w0s[i], wi1 = w1s[i];
    const float* row = Cov + i * D_PAD;
    const float c0 = row[j0], c1 = row[j1], c2 = v2 ? row[j2] : 0.f;
    acc0 += wi0 * (c0 * wj00 + c1 * wj01 + c2 * wj02);
    acc1 += wi1 * (c0 * wj10 + c1 * wj11 + c2 * wj12);
  }
#pragma unroll
  for (int off = 32; off > 0; off >>= 1) {
    acc0 += __shfl_down(acc0, off);
    acc1 += __shfl_down(acc1, off);
  }
  __shared__ float pr[2][4];
  const int lane = threadIdx.x & 63, wv = threadIdx.x >> 6;
  if (lane == 0) { pr[0][wv] = acc0; pr[1][wv] = acc1; }
  __syncthreads();
  if (threadIdx.x == 0) {
    float v0 = pr[0][0] + pr[0][1] + pr[0][2] + pr[0][3];
    float v1 = pr[1][0] + pr[1][1] + pr[1][2] + pr[1][3];
    alpha[k0]     = g[k0]     * rsqrtf(v0 + BN_EPS);
    alpha[k0 + 1] = g[k0 + 1] * rsqrtf(v1 + BN_EPS);
  }
}

// ---------------- K3c: G[i][j] = sum_k W1[i][k]*alpha1[k]*W2[k][j] ----------------------------
__global__ __launch_bounds__(256) void k3c_G(const float* __restrict__ W1,
                                             const float* __restrict__ alpha1,
                                             const float* __restrict__ W2,
                                             float* __restrict__ G) {
  const int i = blockIdx.x;
  __shared__ float a[512];
  for (int k = threadIdx.x; k < 512; k += 256)
    a[k] = W1[(size_t)i * 512 + k] * alpha1[k];
  __syncthreads();
  const int j = threadIdx.x;
  float acc = 0.f;
#pragma unroll 8
  for (int k = 0; k < 512; ++k) acc += a[k] * W2[(size_t)k * 256 + j];
  G[(size_t)i * 256 + j] = acc;
}

// ---------------- K3e: gw[i] = sum_j G[i][j]*alpha2[j];  consts = bias + sum(be2) - mu.gw -----
__global__ __launch_bounds__(256) void k3e_final(const float* __restrict__ G,
                                                 const float* __restrict__ alpha2,
                                                 const float* __restrict__ mu,
                                                 const float* __restrict__ be2,
                                                 const float* __restrict__ bias,
                                                 float* __restrict__ gw,
                                                 float* __restrict__ consts) {
  __shared__ float a2[256];
  __shared__ float gws[640];
  a2[threadIdx.x] = alpha2[threadIdx.x];
  __syncthreads();
  for (int i = threadIdx.x; i < 640; i += 256) {
    float acc = 0.f;
    if (i < 624) {
      const float* gr = G + (size_t)i * 256;
#pragma unroll 8
      for (int j = 0; j < 256; ++j) acc += gr[j] * a2[j];
    }
    gw[i] = acc;
    gws[i] = acc;
  }
  __syncthreads();
  float pm = 0.f;
  for (int i = threadIdx.x; i < 624; i += 256) pm += mu[i] * gws[i];
  float val = be2[threadIdx.x] - pm;
#pragma unroll
  for (int off = 32; off > 0; off >>= 1) val += __shfl_down(val, off);
  __shared__ float pr[4];
  const int lane = threadIdx.x & 63, wv = threadIdx.x >> 6;
  if (lane == 0) pr[wv] = val;
  __syncthreads();
  if (threadIdx.x == 0) consts[0] = bias[0] + pr[0] + pr[1] + pr[2] + pr[3];
}

// ---------------- K5: out[b] = consts + fs[b] + sum_m gw[m] * XT[m][b]  (coalesced GEMV) ------
__global__ __launch_bounds__(256) void k5_dot(const unsigned short* __restrict__ XT,
                                              const float* __restrict__ gw,
                                              const float* __restrict__ fs,
                                              const float* __restrict__ consts,
                                              float* __restrict__ out) {
  __shared__ float g[624];
  for (int m = threadIdx.x; m < 624; m += 256) g[m] = gw[m];
  __syncthreads();
  const int b = blockIdx.x * 256 + threadIdx.x;
  const unsigned short* col = XT + b;
  float acc = 0.f;
#pragma unroll 8
  for (int m = 0; m < 624; ++m) {
    unsigned int u = (unsigned int)col[(size_t)m * B_ROWS] << 16;
    acc += __uint_as_float(u) * g[m];
  }
  out[b] = acc + fs[b] + consts[0];
}

// ---------------- host launch ----------------------------------------------------------------
extern "C" void kernel_launch(void* const* d_in, const int* in_sizes, int n_in,
                              void* d_out, int out_size, void* d_ws, size_t ws_size,
                              hipStream_t stream) {
  const int*   Xi   = (const int*)d_in[0];
  const float* Xv   = (const float*)d_in[1];
  const float* emb1 = (const float*)d_in[2];
  const float* emb2 = (const float*)d_in[3];
  const float* W1   = (const float*)d_in[4];
  const float* g1   = (const float*)d_in[6];
  const float* W2   = (const float*)d_in[8];
  const float* g2   = (const float*)d_in[10];
  const float* be2  = (const float*)d_in[11];
  const float* bias = (const float*)d_in[12];
  float* out = (float*)d_out;
  char* ws = (char*)d_ws;

  const size_t OFF_XT  = 0;
  const size_t OFF_M   = OFF_XT + (size_t)640 * 65536 * 2;  // 83,886,080
  const size_t OFF_COV = OFF_M + (size_t)640 * 640 * 4;
  const size_t OFF_MU  = OFF_COV + (size_t)640 * 640 * 4;
  const size_t OFF_A1  = OFF_MU + 640 * 4;
  const size_t OFF_A2  = OFF_A1 + 512 * 4;
  const size_t OFF_G   = OFF_A2 + 256 * 4;
  const size_t OFF_GW  = OFF_G + (size_t)624 * 256 * 4;
  const size_t OFF_CN  = OFF_GW + 640 * 4;
  const size_t OFF_FS  = OFF_CN + 256;
  // total = OFF_FS + 65536*4  ~= 88 MB

  unsigned short* XT = (unsigned short*)(ws + OFF_XT);
  float* M   = (float*)(ws + OFF_M);
  float* COV = (float*)(ws + OFF_COV);
  float* MU  = (float*)(ws + OFF_MU);
  float* A1  = (float*)(ws + OFF_A1);
  float* A2  = (float*)(ws + OFF_A2);
  float* G   = (float*)(ws + OFF_G);
  float* GW  = (float*)(ws + OFF_GW);
  float* CN  = (float*)(ws + OFF_CN);
  float* FS  = (float*)(ws + OFF_FS);

  k1_gather<<<4096, 256, 0, stream>>>(Xi, Xv, emb1, emb2, XT, FS, M);
  k2_syrk<<<15 * KSPLIT, 256, 0, stream>>>(XT, M);
  k3a_cov<<<640, 256, 0, stream>>>(M, COV, MU);
  qform<<<256, 256, 0, stream>>>(COV, W1, 512, g1, A1);
  k3c_G<<<624, 256, 0, stream>>>(W1, A1, W2, G);
  qform<<<128, 256, 0, stream>>>(COV, G, 256, g2, A2);
  k3e_final<<<1, 256, 0, stream>>>(G, A2, MU, be2, bias, GW, CN);
  k5_dot<<<256, 256, 0, stream>>>(XT, GW, FS, CN, out);
}

// Round 5
// 360.381 us; speedup vs baseline: 1.1115x; 1.1115x over previous
//
#include <hip/hip_runtime.h>

#define B_ROWS 65536
#define F_FEAT 39
#define V_VOC  100000
#define D_PAD  640
#define BN_EPS 1e-5f

typedef __bf16 bf16x8 __attribute__((ext_vector_type(8)));
typedef float  f32x16 __attribute__((ext_vector_type(16)));

__device__ __forceinline__ unsigned short toBF(float x) {
  unsigned int u = __float_as_uint(x);
  u += 0x7fffu + ((u >> 16) & 1u);
  return (unsigned short)(u >> 16);
}

// ---------------- K1: gather fm2 via float4 (4 lanes/row-slice), write Xt, fs = FM2 ----------
// R3 (8B/lane, 30% occ) = 150us; R4 (4B/lane, 56% occ) = 170us -> request-throughput bound.
// This version: 16B/lane float4, instructions /4 vs R4, same 26KB-LDS occupancy shape.
// Lane decomposition within a 16-lane row group: seg = lane&3 (4-float segment of the 16-dim
// embedding), fo = lane>>2 (covers f = 4*it + fo). emb1 moved to k5.
__global__ __launch_bounds__(256) void k1_gather(
    const int* __restrict__ Xi, const float* __restrict__ Xv,
    const float* __restrict__ emb2,
    unsigned short* __restrict__ XT, float* __restrict__ fs,
    float* __restrict__ Mz) {
  if (threadIdx.x < 100)
    Mz[(size_t)blockIdx.x * 100 + threadIdx.x] = 0.f;

  const int b0 = blockIdx.x * 16;
  __shared__ int            sIdx[16][40];
  __shared__ float          sXv[16][40];
  __shared__ unsigned short xt[16][648];   // 648-short stride: +4 bank shift per row

  for (int u = threadIdx.x; u < 16 * 39; u += 256) {
    int r = u / 39, f = u - r * 39;
    sIdx[r][f] = Xi[(size_t)(b0 + r) * 39 + f];
    sXv[r][f]  = Xv[(size_t)(b0 + r) * 39 + f];
  }
  __syncthreads();

  const int r   = threadIdx.x >> 4;
  const int l16 = threadIdx.x & 15;
  const int seg = l16 & 3;   // which 4-float segment of the 16 dims
  const int fo  = l16 >> 2;  // f = 4*it + fo

  float4 sv = {0.f, 0.f, 0.f, 0.f};  // per-dim partial sums (dims seg*4..seg*4+3)
  float  ss = 0.f;                   // sum of squares (scalar, order-free)
#pragma unroll
  for (int it = 0; it < 10; ++it) {
    const int f = it * 4 + fo;
    if (f < 39) {
      const int   id = sIdx[r][f];
      const float xv = sXv[r][f];
      const float4 v = *reinterpret_cast<const float4*>(
          emb2 + ((size_t)f * V_VOC + id) * 16 + seg * 4);
      const float a0 = v.x * xv, a1 = v.y * xv, a2 = v.z * xv, a3 = v.w * xv;
      sv.x += a0; sv.y += a1; sv.z += a2; sv.w += a3;
      ss += a0 * a0 + a1 * a1 + a2 * a2 + a3 * a3;
      uint2 pk;
      pk.x = (unsigned int)toBF(a0) | ((unsigned int)toBF(a1) << 16);
      pk.y = (unsigned int)toBF(a2) | ((unsigned int)toBF(a3) << 16);
      *reinterpret_cast<uint2*>(&xt[r][f * 16 + seg * 4]) = pk;
    }
  }
  // complete per-dim sums over fo (lane bits 2,3), THEN square, then sum over seg (bits 0,1)
  sv.x += __shfl_xor(sv.x, 4); sv.y += __shfl_xor(sv.y, 4);
  sv.z += __shfl_xor(sv.z, 4); sv.w += __shfl_xor(sv.w, 4);
  sv.x += __shfl_xor(sv.x, 8); sv.y += __shfl_xor(sv.y, 8);
  sv.z += __shfl_xor(sv.z, 8); sv.w += __shfl_xor(sv.w, 8);
  float s2 = sv.x * sv.x + sv.y * sv.y + sv.z * sv.z + sv.w * sv.w;
  s2 += __shfl_xor(s2, 1);
  s2 += __shfl_xor(s2, 2);
  ss += __shfl_xor(ss, 1);
  ss += __shfl_xor(ss, 2);
  ss += __shfl_xor(ss, 4);
  ss += __shfl_xor(ss, 8);
  if (l16 == 0) fs[b0 + r] = 0.5f * (s2 - ss);
  __syncthreads();

  // write Xt[m][b0..b0+15]; m=624 -> ones column, 625..639 -> zeros
  for (int m = threadIdx.x; m < 640; m += 256) {
    unsigned short* dst = XT + (size_t)m * B_ROWS + b0;
    unsigned int q2[8];
    if (m < 624) {
#pragma unroll
      for (int rr = 0; rr < 8; ++rr)
        q2[rr] = (unsigned int)xt[2 * rr][m] | ((unsigned int)xt[2 * rr + 1][m] << 16);
    } else {
      unsigned int fill = (m == 624) ? 0x3f803f80u : 0u;
#pragma unroll
      for (int rr = 0; rr < 8; ++rr) q2[rr] = fill;
    }
    uint4 w0, w1;
    w0.x = q2[0]; w0.y = q2[1]; w0.z = q2[2]; w0.w = q2[3];
    w1.x = q2[4]; w1.y = q2[5]; w1.z = q2[6]; w1.w = q2[7];
    *reinterpret_cast<uint4*>(dst)     = w0;
    *reinterpret_cast<uint4*>(dst + 8) = w1;
  }
}

// ---------------- K2: M += Xt * Xt^T  (640x640, symmetric tiles ti<=tj), bf16 MFMA ----------
#define KSPLIT 32
__global__ __launch_bounds__(256) void k2_syrk(const unsigned short* __restrict__ XT,
                                               float* __restrict__ M) {
  const int ks = blockIdx.x & (KSPLIT - 1);
  int pair = blockIdx.x >> 5;
  int ti = 0, p = pair;
  while (p >= 5 - ti) { p -= 5 - ti; ++ti; }
  const int tj = ti + p;

  __shared__ unsigned short pa[128 * 64];
  __shared__ unsigned short pb[128 * 64];

  const int lane = threadIdx.x & 63, wid = threadIdx.x >> 6;
  const int wm = wid >> 1, wn = wid & 1;
  const int rl = lane & 31, hh = lane >> 5;

  f32x16 acc00, acc01, acc10, acc11;
#pragma unroll
  for (int i = 0; i < 16; ++i) { acc00[i] = 0.f; acc01[i] = 0.f; acc10[i] = 0.f; acc11[i] = 0.f; }

  const int krange = B_ROWS / KSPLIT;  // 2048
  const int kbase = ks * krange;

  for (int kt = 0; kt < krange; kt += 64) {
    const int k0 = kbase + kt;
#pragma unroll
    for (int g2 = 0; g2 < 4; ++g2) {
      const int g = threadIdx.x + g2 * 256;
      const int r = g >> 3, j = g & 7;
      uint4 va = *reinterpret_cast<const uint4*>(XT + (size_t)(ti * 128 + r) * B_ROWS + k0 + j * 8);
      *reinterpret_cast<uint4*>((char*)pa + r * 128 + ((j ^ (r & 7)) << 4)) = va;
      uint4 vb = *reinterpret_cast<const uint4*>(XT + (size_t)(tj * 128 + r) * B_ROWS + k0 + j * 8);
      *reinterpret_cast<uint4*>((char*)pb + r * 128 + ((j ^ (r & 7)) << 4)) = vb;
    }
    __syncthreads();
#pragma unroll
    for (int kc = 0; kc < 4; ++kc) {
      const int ra0 = wm * 64 + rl, ra1 = wm * 64 + 32 + rl;
      const int rb0 = wn * 64 + rl, rb1 = wn * 64 + 32 + rl;
      bf16x8 a0 = *reinterpret_cast<const bf16x8*>((char*)pa + ra0 * 128 + (((kc * 2 + hh) ^ (ra0 & 7)) << 4));
      bf16x8 a1 = *reinterpret_cast<const bf16x8*>((char*)pa + ra1 * 128 + (((kc * 2 + hh) ^ (ra1 & 7)) << 4));
      bf16x8 b0 = *reinterpret_cast<const bf16x8*>((char*)pb + rb0 * 128 + (((kc * 2 + hh) ^ (rb0 & 7)) << 4));
      bf16x8 b1 = *reinterpret_cast<const bf16x8*>((char*)pb + rb1 * 128 + (((kc * 2 + hh) ^ (rb1 & 7)) << 4));
      acc00 = __builtin_amdgcn_mfma_f32_32x32x16_bf16(a0, b0, acc00, 0, 0, 0);
      acc01 = __builtin_amdgcn_mfma_f32_32x32x16_bf16(a0, b1, acc01, 0, 0, 0);
      acc10 = __builtin_amdgcn_mfma_f32_32x32x16_bf16(a1, b0, acc10, 0, 0, 0);
      acc11 = __builtin_amdgcn_mfma_f32_32x32x16_bf16(a1, b1, acc11, 0, 0, 0);
    }
    __syncthreads();
  }

#pragma unroll
  for (int rr = 0; rr < 16; ++rr) {
    const int rloc = (rr & 3) + ((rr >> 2) << 3) + hh * 4;
    const int row0 = ti * 128 + wm * 64 + rloc;
    const int row1 = row0 + 32;
    const int col0 = tj * 128 + wn * 64 + rl;
    atomicAdd(&M[row0 * D_PAD + col0], acc00[rr]);
    atomicAdd(&M[row0 * D_PAD + col0 + 32], acc01[rr]);
    atomicAdd(&M[row1 * D_PAD + col0], acc10[rr]);
    atomicAdd(&M[row1 * D_PAD + col0 + 32], acc11[rr]);
  }
}

// ---------------- K3a: Cov + mu from M --------------------------------------------------------
__device__ __forceinline__ float fetchM(const float* M, int a, int b) {
  if ((a >> 7) > (b >> 7)) { int t = a; a = b; b = t; }
  return M[a * D_PAD + b];
}
__global__ void k3a_cov(const float* __restrict__ M, float* __restrict__ Cov,
                        float* __restrict__ mu) {
  const int i = blockIdx.x;
  const float inv = 1.f / 65536.f;
  const float mui = fetchM(M, 624, i) * inv;
  for (int j = threadIdx.x; j < D_PAD; j += 256) {
    float muj = fetchM(M, 624, j) * inv;
    Cov[i * D_PAD + j] = fetchM(M, i, j) * inv - mui * muj;
    if (i == 0) mu[j] = muj;
  }
}

// ---------------- qform: alpha[k] = g[k] * rsqrt( W[:,k]^T Cov W[:,k] + eps ), 2 k's/block -----
__global__ __launch_bounds__(256) void qform(const float* __restrict__ Cov,
                                             const float* __restrict__ W, const int ldw,
                                             const float* __restrict__ g,
                                             float* __restrict__ alpha) {
  const int k0 = blockIdx.x * 2;
  __shared__ float w0s[624], w1s[624];
  for (int i = threadIdx.x; i < 624; i += 256) {
    w0s[i] = W[(size_t)i * ldw + k0];
    w1s[i] = W[(size_t)i * ldw + k0 + 1];
  }
  __syncthreads();
  const int j0 = threadIdx.x, j1 = threadIdx.x + 256, j2 = threadIdx.x + 512;
  const bool v2 = (j2 < 624);
  const float wj00 = w0s[j0], wj01 = w0s[j1], wj02 = v2 ? w0s[j2] : 0.f;
  const float wj10 = w1s[j0], wj11 = w1s[j1], wj12 = v2 ? w1s[j2] : 0.f;
  float acc0 = 0.f, acc1 = 0.f;
  for (int i = 0; i < 624; ++i) {
    const float wi0 = w0s[i], wi1 = w1s[i];
    const float* row = Cov + i * D_PAD;
    const float c0 = row[j0], c1 = row[j1], c2 = v2 ? row[j2] : 0.f;
    acc0 += wi0 * (c0 * wj00 + c1 * wj01 + c2 * wj02);
    acc1 += wi1 * (c0 * wj10 + c1 * wj11 + c2 * wj12);
  }
#pragma unroll
  for (int off = 32; off > 0; off >>= 1) {
    acc0 += __shfl_down(acc0, off);
    acc1 += __shfl_down(acc1, off);
  }
  __shared__ float pr[2][4];
  const int lane = threadIdx.x & 63, wv = threadIdx.x >> 6;
  if (lane == 0) { pr[0][wv] = acc0; pr[1][wv] = acc1; }
  __syncthreads();
  if (threadIdx.x == 0) {
    float v0 = pr[0][0] + pr[0][1] + pr[0][2] + pr[0][3];
    float v1 = pr[1][0] + pr[1][1] + pr[1][2] + pr[1][3];
    alpha[k0]     = g[k0]     * rsqrtf(v0 + BN_EPS);
    alpha[k0 + 1] = g[k0 + 1] * rsqrtf(v1 + BN_EPS);
  }
}

// ---------------- K3c: G[i][j] = sum_k W1[i][k]*alpha1[k]*W2[k][j] ----------------------------
__global__ __launch_bounds__(256) void k3c_G(const float* __restrict__ W1,
                                             const float* __restrict__ alpha1,
                                             const float* __restrict__ W2,
                                             float* __restrict__ G) {
  const int i = blockIdx.x;
  __shared__ float a[512];
  for (int k = threadIdx.x; k < 512; k += 256)
    a[k] = W1[(size_t)i * 512 + k] * alpha1[k];
  __syncthreads();
  const int j = threadIdx.x;
  float acc = 0.f;
#pragma unroll 8
  for (int k = 0; k < 512; ++k) acc += a[k] * W2[(size_t)k * 256 + j];
  G[(size_t)i * 256 + j] = acc;
}

// ---------------- K3e: gw[i] = sum_j G[i][j]*alpha2[j];  consts = bias + sum(be2) - mu.gw -----
__global__ __launch_bounds__(256) void k3e_final(const float* __restrict__ G,
                                                 const float* __restrict__ alpha2,
                                                 const float* __restrict__ mu,
                                                 const float* __restrict__ be2,
                                                 const float* __restrict__ bias,
                                                 float* __restrict__ gw,
                                                 float* __restrict__ consts) {
  __shared__ float a2[256];
  __shared__ float gws[640];
  a2[threadIdx.x] = alpha2[threadIdx.x];
  __syncthreads();
  for (int i = threadIdx.x; i < 640; i += 256) {
    float acc = 0.f;
    if (i < 624) {
      const float* gr = G + (size_t)i * 256;
#pragma unroll 8
      for (int j = 0; j < 256; ++j) acc += gr[j] * a2[j];
    }
    gw[i] = acc;
    gws[i] = acc;
  }
  __syncthreads();
  float pm = 0.f;
  for (int i = threadIdx.x; i < 624; i += 256) pm += mu[i] * gws[i];
  float val = be2[threadIdx.x] - pm;
#pragma unroll
  for (int off = 32; off > 0; off >>= 1) val += __shfl_down(val, off);
  __shared__ float pr[4];
  const int lane = threadIdx.x & 63, wv = threadIdx.x >> 6;
  if (lane == 0) pr[wv] = val;
  __syncthreads();
  if (threadIdx.x == 0) consts[0] = bias[0] + pr[0] + pr[1] + pr[2] + pr[3];
}

// ---------------- K5: out[b] = consts + fs[b] + first-order(emb1) + gw . XT[:,b] -------------
// 128 b's per block, 2 threads per b (h = half). Takes over the emb1 gather (L3-resident,
// latency hidden under the streaming XT GEMV).
__global__ __launch_bounds__(256) void k5_out(const int* __restrict__ Xi,
                                              const float* __restrict__ Xv,
                                              const float* __restrict__ emb1,
                                              const unsigned short* __restrict__ XT,
                                              const float* __restrict__ gw,
                                              const float* __restrict__ fs,
                                              const float* __restrict__ consts,
                                              float* __restrict__ out) {
  const int b0 = blockIdx.x * 128;
  __shared__ int   si[128][40];
  __shared__ float sx[128][40];
  __shared__ float g[624];
  for (int m = threadIdx.x; m < 624; m += 256) g[m] = gw[m];
  for (int u = threadIdx.x; u < 128 * 39; u += 256) {
    int rr = u / 39, ff = u - rr * 39;
    si[rr][ff] = Xi[(size_t)b0 * 39 + u];
    sx[rr][ff] = Xv[(size_t)b0 * 39 + u];
  }
  __syncthreads();
  const int r = threadIdx.x >> 1, h = threadIdx.x & 1;
  const int b = b0 + r;
  float acc = 0.f;
  const unsigned short* col = XT + b;
  const int m0 = h * 312;
#pragma unroll 8
  for (int m = m0; m < m0 + 312; ++m) {
    unsigned int u = (unsigned int)col[(size_t)m * B_ROWS] << 16;
    acc += __uint_as_float(u) * g[m];
  }
  const int fb = h ? 20 : 0, fe = h ? 39 : 20;
  for (int f = fb; f < fe; ++f)
    acc += emb1[(size_t)f * V_VOC + si[r][f]] * sx[r][f];
  acc += __shfl_xor(acc, 1);
  if (h == 0) out[b] = acc + fs[b] + consts[0];
}

// ---------------- host launch ----------------------------------------------------------------
extern "C" void kernel_launch(void* const* d_in, const int* in_sizes, int n_in,
                              void* d_out, int out_size, void* d_ws, size_t ws_size,
                              hipStream_t stream) {
  const int*   Xi   = (const int*)d_in[0];
  const float* Xv   = (const float*)d_in[1];
  const float* emb1 = (const float*)d_in[2];
  const float* emb2 = (const float*)d_in[3];
  const float* W1   = (const float*)d_in[4];
  const float* g1   = (const float*)d_in[6];
  const float* W2   = (const float*)d_in[8];
  const float* g2   = (const float*)d_in[10];
  const float* be2  = (const float*)d_in[11];
  const float* bias = (const float*)d_in[12];
  float* out = (float*)d_out;
  char* ws = (char*)d_ws;

  const size_t OFF_XT  = 0;
  const size_t OFF_M   = OFF_XT + (size_t)640 * 65536 * 2;  // 83,886,080
  const size_t OFF_COV = OFF_M + (size_t)640 * 640 * 4;
  const size_t OFF_MU  = OFF_COV + (size_t)640 * 640 * 4;
  const size_t OFF_A1  = OFF_MU + 640 * 4;
  const size_t OFF_A2  = OFF_A1 + 512 * 4;
  const size_t OFF_G   = OFF_A2 + 256 * 4;
  const size_t OFF_GW  = OFF_G + (size_t)624 * 256 * 4;
  const size_t OFF_CN  = OFF_GW + 640 * 4;
  const size_t OFF_FS  = OFF_CN + 256;
  // total = OFF_FS + 65536*4  ~= 88 MB

  unsigned short* XT = (unsigned short*)(ws + OFF_XT);
  float* M   = (float*)(ws + OFF_M);
  float* COV = (float*)(ws + OFF_COV);
  float* MU  = (float*)(ws + OFF_MU);
  float* A1  = (float*)(ws + OFF_A1);
  float* A2  = (float*)(ws + OFF_A2);
  float* G   = (float*)(ws + OFF_G);
  float* GW  = (float*)(ws + OFF_GW);
  float* CN  = (float*)(ws + OFF_CN);
  float* FS  = (float*)(ws + OFF_FS);

  k1_gather<<<4096, 256, 0, stream>>>(Xi, Xv, emb2, XT, FS, M);
  k2_syrk<<<15 * KSPLIT, 256, 0, stream>>>(XT, M);
  k3a_cov<<<640, 256, 0, stream>>>(M, COV, MU);
  qform<<<256, 256, 0, stream>>>(COV, W1, 512, g1, A1);
  k3c_G<<<624, 256, 0, stream>>>(W1, A1, W2, G);
  qform<<<128, 256, 0, stream>>>(COV, G, 256, g2, A2);
  k3e_final<<<1, 256, 0, stream>>>(G, A2, MU, be2, bias, GW, CN);
  k5_out<<<512, 256, 0, stream>>>(Xi, Xv, emb1, XT, GW, FS, CN, out);
}

// Round 6
// 343.385 us; speedup vs baseline: 1.1666x; 1.0495x over previous
//
#include <hip/hip_runtime.h>

#define B_ROWS 65536
#define F_FEAT 39
#define V_VOC  100000
#define D_PAD  640
#define BN_EPS 1e-5f

typedef __bf16 bf16x8 __attribute__((ext_vector_type(8)));
typedef float  f32x16 __attribute__((ext_vector_type(16)));

__device__ __forceinline__ unsigned short toBF(float x) {
  unsigned int u = __float_as_uint(x);
  u += 0x7fffu + ((u >> 16) & 1u);
  return (unsigned short)(u >> 16);
}

// ---------------- K0: transpose Xi/Xv to f-major; zero M; fill XT pad rows 624..639 ----------
__global__ __launch_bounds__(256) void k0_prep(
    const int* __restrict__ Xi, const float* __restrict__ Xv,
    int* __restrict__ XiT, float* __restrict__ XvT,
    float* __restrict__ M, unsigned short* __restrict__ XT) {
  // zero M: 512 blocks x 800 floats = 640*640
  for (int i = threadIdx.x; i < 800; i += 256)
    M[(size_t)blockIdx.x * 800 + i] = 0.f;

  const int b0 = blockIdx.x * 128;
  // XT pad rows: 624 = ones (bf16 1.0), 625..639 = zeros
  for (int u = threadIdx.x; u < 16 * 128; u += 256) {
    int m = 624 + (u >> 7), j = u & 127;
    XT[(size_t)m * B_ROWS + b0 + j] = (m == 624) ? (unsigned short)0x3f80 : (unsigned short)0;
  }

  __shared__ int   ti[128][41];
  __shared__ float tv[128][41];
  for (int u = threadIdx.x; u < 128 * 39; u += 256) {
    int r = u / 39, f = u - r * 39;
    ti[r][f] = Xi[(size_t)b0 * 39 + u];
    tv[r][f] = Xv[(size_t)b0 * 39 + u];
  }
  __syncthreads();
  for (int u = threadIdx.x; u < 39 * 128; u += 256) {
    int f = u >> 7, j = u & 127;
    XiT[(size_t)f * B_ROWS + b0 + j] = ti[j][f];
    XvT[(size_t)f * B_ROWS + b0 + j] = tv[j][f];
  }
}

// ---------------- K1f: f-major gather. Block = (f, 2048-row chunk). ---------------------------
// All gathers of a block fall in one 6.4 MB emb2 f-slice; ~256 active blocks span ~8 f's
// (~50 MB window) -> L3-resident, ~20 touches per 2KB DRAM page (vs 0.65 when b-major).
// Writes XT[f*16+dim][b] directly via per-stripe LDS micro-transpose (64 b's/stripe).
#define CHUNK 2048
__global__ __launch_bounds__(256) void k1f_gather(
    const int* __restrict__ XiT, const float* __restrict__ XvT,
    const float* __restrict__ emb2, unsigned short* __restrict__ XT) {
  const int f = blockIdx.x >> 5;       // 39 f's
  const int c = blockIdx.x & 31;       // 32 chunks
  const int b0 = c * CHUNK;
  const float* ef = emb2 + (size_t)f * V_VOC * 16;
  const int*   xi = XiT + (size_t)f * B_ROWS + b0;
  const float* xv = XvT + (size_t)f * B_ROWS + b0;
  unsigned short* xtBase = XT + (size_t)(f * 16) * B_ROWS + b0;

  __shared__ unsigned short xs[2][16][68];

  const int seg = threadIdx.x & 3;        // 4-float segment of 16 dims
  const int bi  = threadIdx.x >> 2;       // 0..63 within stripe
  const int dim = threadIdx.x >> 4;       // drain: 0..15
  const int prt = threadIdx.x & 15;       // drain: 16 x 8B = 128B per dim row

  // software pipeline: idx 2 ahead, gather 1 ahead
  int   idA = xi[bi],      idB = xi[64 + bi];
  float xvA = xv[bi],      xvB = xv[64 + bi];
  float4 v = *reinterpret_cast<const float4*>(ef + (size_t)idA * 16 + seg * 4);

  for (int s = 0; s < CHUNK / 64; ++s) {
    const float4 cur = v;
    const float  xvc = xvA;
    idA = idB; xvA = xvB;
    if (s + 2 < CHUNK / 64) {
      idB = xi[(s + 2) * 64 + bi];
      xvB = xv[(s + 2) * 64 + bi];
    }
    if (s + 1 < CHUNK / 64)
      v = *reinterpret_cast<const float4*>(ef + (size_t)idA * 16 + seg * 4);

    // scale + pack into stripe buffer
    const int bf = s & 1;
    xs[bf][seg * 4 + 0][bi] = toBF(cur.x * xvc);
    xs[bf][seg * 4 + 1][bi] = toBF(cur.y * xvc);
    xs[bf][seg * 4 + 2][bi] = toBF(cur.z * xvc);
    xs[bf][seg * 4 + 3][bi] = toBF(cur.w * xvc);
    __syncthreads();
    // drain: 16 dims x 64 shorts -> XT rows (coalesced 128B per dim)
    uint2 w = *reinterpret_cast<const uint2*>(&xs[bf][dim][prt * 4]);
    *reinterpret_cast<uint2*>(xtBase + (size_t)dim * B_ROWS + s * 64 + prt * 4) = w;
    // next iteration writes xs[bf^1], drained two stripes ago; the barrier above
    // also orders that reuse.
  }
}

// ---------------- K2: M += Xt * Xt^T  (640x640, symmetric tiles ti<=tj), bf16 MFMA ----------
// Block swizzle: physical p -> xcd = p&7 (assumed round-robin XCD dispatch); all 15 tile-pairs
// of one K-slice (2.5 MB of XT) run on the same XCD -> L2-resident re-reads.
#define KSPLIT 32
__global__ __launch_bounds__(256) void k2_syrk(const unsigned short* __restrict__ XT,
                                               float* __restrict__ M) {
  const int p = blockIdx.x;
  const int xcd = p & 7;
  const int ks = ((p >> 3) / 15) * 8 + xcd;   // 0..31
  int pair = (p >> 3) % 15;
  int ti = 0;
  while (pair >= 5 - ti) { pair -= 5 - ti; ++ti; }
  const int tj = ti + pair;

  __shared__ unsigned short pa[128 * 64];
  __shared__ unsigned short pb[128 * 64];

  const int lane = threadIdx.x & 63, wid = threadIdx.x >> 6;
  const int wm = wid >> 1, wn = wid & 1;
  const int rl = lane & 31, hh = lane >> 5;

  f32x16 acc00, acc01, acc10, acc11;
#pragma unroll
  for (int i = 0; i < 16; ++i) { acc00[i] = 0.f; acc01[i] = 0.f; acc10[i] = 0.f; acc11[i] = 0.f; }

  const int krange = B_ROWS / KSPLIT;  // 2048
  const int kbase = ks * krange;

  for (int kt = 0; kt < krange; kt += 64) {
    const int k0 = kbase + kt;
#pragma unroll
    for (int g2 = 0; g2 < 4; ++g2) {
      const int g = threadIdx.x + g2 * 256;
      const int r = g >> 3, j = g & 7;
      uint4 va = *reinterpret_cast<const uint4*>(XT + (size_t)(ti * 128 + r) * B_ROWS + k0 + j * 8);
      *reinterpret_cast<uint4*>((char*)pa + r * 128 + ((j ^ (r & 7)) << 4)) = va;
      uint4 vb = *reinterpret_cast<const uint4*>(XT + (size_t)(tj * 128 + r) * B_ROWS + k0 + j * 8);
      *reinterpret_cast<uint4*>((char*)pb + r * 128 + ((j ^ (r & 7)) << 4)) = vb;
    }
    __syncthreads();
#pragma unroll
    for (int kc = 0; kc < 4; ++kc) {
      const int ra0 = wm * 64 + rl, ra1 = wm * 64 + 32 + rl;
      const int rb0 = wn * 64 + rl, rb1 = wn * 64 + 32 + rl;
      bf16x8 a0 = *reinterpret_cast<const bf16x8*>((char*)pa + ra0 * 128 + (((kc * 2 + hh) ^ (ra0 & 7)) << 4));
      bf16x8 a1 = *reinterpret_cast<const bf16x8*>((char*)pa + ra1 * 128 + (((kc * 2 + hh) ^ (ra1 & 7)) << 4));
      bf16x8 b0 = *reinterpret_cast<const bf16x8*>((char*)pb + rb0 * 128 + (((kc * 2 + hh) ^ (rb0 & 7)) << 4));
      bf16x8 b1 = *reinterpret_cast<const bf16x8*>((char*)pb + rb1 * 128 + (((kc * 2 + hh) ^ (rb1 & 7)) << 4));
      acc00 = __builtin_amdgcn_mfma_f32_32x32x16_bf16(a0, b0, acc00, 0, 0, 0);
      acc01 = __builtin_amdgcn_mfma_f32_32x32x16_bf16(a0, b1, acc01, 0, 0, 0);
      acc10 = __builtin_amdgcn_mfma_f32_32x32x16_bf16(a1, b0, acc10, 0, 0, 0);
      acc11 = __builtin_amdgcn_mfma_f32_32x32x16_bf16(a1, b1, acc11, 0, 0, 0);
    }
    __syncthreads();
  }

#pragma unroll
  for (int rr = 0; rr < 16; ++rr) {
    const int rloc = (rr & 3) + ((rr >> 2) << 3) + hh * 4;
    const int row0 = ti * 128 + wm * 64 + rloc;
    const int row1 = row0 + 32;
    const int col0 = tj * 128 + wn * 64 + rl;
    atomicAdd(&M[row0 * D_PAD + col0], acc00[rr]);
    atomicAdd(&M[row0 * D_PAD + col0 + 32], acc01[rr]);
    atomicAdd(&M[row1 * D_PAD + col0], acc10[rr]);
    atomicAdd(&M[row1 * D_PAD + col0 + 32], acc11[rr]);
  }
}

// ---------------- K3a: Cov + mu from M --------------------------------------------------------
__device__ __forceinline__ float fetchM(const float* M, int a, int b) {
  if ((a >> 7) > (b >> 7)) { int t = a; a = b; b = t; }
  return M[a * D_PAD + b];
}
__global__ void k3a_cov(const float* __restrict__ M, float* __restrict__ Cov,
                        float* __restrict__ mu) {
  const int i = blockIdx.x;
  const float inv = 1.f / 65536.f;
  const float mui = fetchM(M, 624, i) * inv;
  for (int j = threadIdx.x; j < D_PAD; j += 256) {
    float muj = fetchM(M, 624, j) * inv;
    Cov[i * D_PAD + j] = fetchM(M, i, j) * inv - mui * muj;
    if (i == 0) mu[j] = muj;
  }
}

// ---------------- qform: alpha[k] = g[k] * rsqrt( W[:,k]^T Cov W[:,k] + eps ), 2 k's/block -----
__global__ __launch_bounds__(256) void qform(const float* __restrict__ Cov,
                                             const float* __restrict__ W, const int ldw,
                                             const float* __restrict__ g,
                                             float* __restrict__ alpha) {
  const int k0 = blockIdx.x * 2;
  __shared__ float w0s[624], w1s[624];
  for (int i = threadIdx.x; i < 624; i += 256) {
    w0s[i] = W[(size_t)i * ldw + k0];
    w1s[i] = W[(size_t)i * ldw + k0 + 1];
  }
  __syncthreads();
  const int j0 = threadIdx.x, j1 = threadIdx.x + 256, j2 = threadIdx.x + 512;
  const bool v2 = (j2 < 624);
  const float wj00 = w0s[j0], wj01 = w0s[j1], wj02 = v2 ? w0s[j2] : 0.f;
  const float wj10 = w1s[j0], wj11 = w1s[j1], wj12 = v2 ? w1s[j2] : 0.f;
  float acc0 = 0.f, acc1 = 0.f;
  for (int i = 0; i < 624; ++i) {
    const float wi0 = w0s[i], wi1 = w1s[i];
    const float* row = Cov + i * D_PAD;
    const float c0 = row[j0], c1 = row[j1], c2 = v2 ? row[j2] : 0.f;
    acc0 += wi0 * (c0 * wj00 + c1 * wj01 + c2 * wj02);
    acc1 += wi1 * (c0 * wj10 + c1 * wj11 + c2 * wj12);
  }
#pragma unroll
  for (int off = 32; off > 0; off >>= 1) {
    acc0 += __shfl_down(acc0, off);
    acc1 += __shfl_down(acc1, off);
  }
  __shared__ float pr[2][4];
  const int lane = threadIdx.x & 63, wv = threadIdx.x >> 6;
  if (lane == 0) { pr[0][wv] = acc0; pr[1][wv] = acc1; }
  __syncthreads();
  if (threadIdx.x == 0) {
    float v0 = pr[0][0] + pr[0][1] + pr[0][2] + pr[0][3];
    float v1 = pr[1][0] + pr[1][1] + pr[1][2] + pr[1][3];
    alpha[k0]     = g[k0]     * rsqrtf(v0 + BN_EPS);
    alpha[k0 + 1] = g[k0 + 1] * rsqrtf(v1 + BN_EPS);
  }
}

// ---------------- K3c: G[i][j] = sum_k W1[i][k]*alpha1[k]*W2[k][j] ----------------------------
__global__ __launch_bounds__(256) void k3c_G(const float* __restrict__ W1,
                                             const float* __restrict__ alpha1,
                                             const float* __restrict__ W2,
                                             float* __restrict__ G) {
  const int i = blockIdx.x;
  __shared__ float a[512];
  for (int k = threadIdx.x; k < 512; k += 256)
    a[k] = W1[(size_t)i * 512 + k] * alpha1[k];
  __syncthreads();
  const int j = threadIdx.x;
  float acc = 0.f;
#pragma unroll 8
  for (int k = 0; k < 512; ++k) acc += a[k] * W2[(size_t)k * 256 + j];
  G[(size_t)i * 256 + j] = acc;
}

// ---------------- K3e: gw[i] = sum_j G[i][j]*alpha2[j];  consts = bias + sum(be2) - mu.gw -----
__global__ __launch_bounds__(256) void k3e_final(const float* __restrict__ G,
                                                 const float* __restrict__ alpha2,
                                                 const float* __restrict__ mu,
                                                 const float* __restrict__ be2,
                                                 const float* __restrict__ bias,
                                                 float* __restrict__ gw,
                                                 float* __restrict__ consts) {
  __shared__ float a2[256];
  __shared__ float gws[640];
  a2[threadIdx.x] = alpha2[threadIdx.x];
  __syncthreads();
  for (int i = threadIdx.x; i < 640; i += 256) {
    float acc = 0.f;
    if (i < 624) {
      const float* gr = G + (size_t)i * 256;
#pragma unroll 8
      for (int j = 0; j < 256; ++j) acc += gr[j] * a2[j];
    }
    gw[i] = acc;
    gws[i] = acc;
  }
  __syncthreads();
  float pm = 0.f;
  for (int i = threadIdx.x; i < 624; i += 256) pm += mu[i] * gws[i];
  float val = be2[threadIdx.x] - pm;
#pragma unroll
  for (int off = 32; off > 0; off >>= 1) val += __shfl_down(val, off);
  __shared__ float pr[4];
  const int lane = threadIdx.x & 63, wv = threadIdx.x >> 6;
  if (lane == 0) pr[wv] = val;
  __syncthreads();
  if (threadIdx.x == 0) consts[0] = bias[0] + pr[0] + pr[1] + pr[2] + pr[3];
}

// ---------------- K5: out[b] = consts + first(emb1) + gw.x + 0.5*(|sum|^2 - ssq) -------------
// One XT-column stream yields linear term AND FM second-order (per-dim sums ps[16] + sumsq).
// 2 threads per b: h=0 -> f 0..19 (m 0..319), h=1 -> f 20..38 (m 320..623).
__global__ __launch_bounds__(256) void k5_out(const int* __restrict__ Xi,
                                              const float* __restrict__ Xv,
                                              const float* __restrict__ emb1,
                                              const unsigned short* __restrict__ XT,
                                              const float* __restrict__ gw,
                                              const float* __restrict__ consts,
                                              float* __restrict__ out) {
  const int b0 = blockIdx.x * 128;
  __shared__ int   si[128][40];
  __shared__ float sx[128][40];
  __shared__ float g[624];
  for (int m = threadIdx.x; m < 624; m += 256) g[m] = gw[m];
  for (int u = threadIdx.x; u < 128 * 39; u += 256) {
    int rr = u / 39, ff = u - rr * 39;
    si[rr][ff] = Xi[(size_t)b0 * 39 + u];
    sx[rr][ff] = Xv[(size_t)b0 * 39 + u];
  }
  __syncthreads();
  const int r = threadIdx.x >> 1, h = threadIdx.x & 1;
  const int b = b0 + r;
  const unsigned short* col = XT + b;

  float lin = 0.f, ssq = 0.f;
  float ps[16];
#pragma unroll
  for (int e = 0; e < 16; ++e) ps[e] = 0.f;

  const int m0 = h ? 320 : 0, m1 = h ? 624 : 320;
  for (int mo = m0; mo < m1; mo += 16) {
#pragma unroll
    for (int e = 0; e < 16; ++e) {
      const int m = mo + e;
      float x = __uint_as_float((unsigned int)col[(size_t)m * B_ROWS] << 16);
      lin += g[m] * x;
      ssq += x * x;
      ps[e] += x;
    }
  }
  // first-order (exact fp32 emb1)
  const int fb = h ? 20 : 0, fe = h ? 39 : 20;
  for (int f = fb; f < fe; ++f)
    lin += emb1[(size_t)f * V_VOC + si[r][f]] * sx[r][f];

  // combine pair: per-dim sums, then square
  float s2 = 0.f;
#pragma unroll
  for (int e = 0; e < 16; ++e) {
    float t = ps[e] + __shfl_xor(ps[e], 1);
    s2 += t * t;
  }
  float tot = lin + 0.5f * (0.5f * s2 - ssq);  // s2 counted once per pair: halve it twice? no:
  // NOTE: s2 is identical on both lanes (full sum), ssq/lin are per-half partials.
  // out = lin_total + 0.5*(s2 - ssq_total); distribute: each lane contributes
  // lin_h + 0.5*(0.5*s2 - ssq_h), summed over the pair gives lin + 0.5*(s2 - ssq).
  tot += __shfl_xor(tot, 1);
  if (h == 0) out[b] = tot + consts[0];
}

// ---------------- host launch ----------------------------------------------------------------
extern "C" void kernel_launch(void* const* d_in, const int* in_sizes, int n_in,
                              void* d_out, int out_size, void* d_ws, size_t ws_size,
                              hipStream_t stream) {
  const int*   Xi   = (const int*)d_in[0];
  const float* Xv   = (const float*)d_in[1];
  const float* emb1 = (const float*)d_in[2];
  const float* emb2 = (const float*)d_in[3];
  const float* W1   = (const float*)d_in[4];
  const float* g1   = (const float*)d_in[6];
  const float* W2   = (const float*)d_in[8];
  const float* g2   = (const float*)d_in[10];
  const float* be2  = (const float*)d_in[11];
  const float* bias = (const float*)d_in[12];
  float* out = (float*)d_out;
  char* ws = (char*)d_ws;

  const size_t OFF_XT  = 0;
  const size_t OFF_M   = OFF_XT + (size_t)640 * 65536 * 2;   // 83.9 MB
  const size_t OFF_COV = OFF_M + (size_t)640 * 640 * 4;
  const size_t OFF_MU  = OFF_COV + (size_t)640 * 640 * 4;
  const size_t OFF_A1  = OFF_MU + 640 * 4;
  const size_t OFF_A2  = OFF_A1 + 512 * 4;
  const size_t OFF_G   = OFF_A2 + 256 * 4;
  const size_t OFF_GW  = OFF_G + (size_t)624 * 256 * 4;
  const size_t OFF_CN  = OFF_GW + 640 * 4;
  const size_t OFF_XIT = OFF_CN + 256;
  const size_t OFF_XVT = OFF_XIT + (size_t)39 * 65536 * 4;   // 10.2 MB
  // total = OFF_XVT + 10.2 MB ~= 108 MB (d_ws ~1 GB per harness poison size)

  unsigned short* XT = (unsigned short*)(ws + OFF_XT);
  float* M   = (float*)(ws + OFF_M);
  float* COV = (float*)(ws + OFF_COV);
  float* MU  = (float*)(ws + OFF_MU);
  float* A1  = (float*)(ws + OFF_A1);
  float* A2  = (float*)(ws + OFF_A2);
  float* G   = (float*)(ws + OFF_G);
  float* GW  = (float*)(ws + OFF_GW);
  float* CN  = (float*)(ws + OFF_CN);
  int*   XIT = (int*)(ws + OFF_XIT);
  float* XVT = (float*)(ws + OFF_XVT);

  k0_prep<<<512, 256, 0, stream>>>(Xi, Xv, XIT, XVT, M, XT);
  k1f_gather<<<39 * 32, 256, 0, stream>>>(XIT, XVT, emb2, XT);
  k2_syrk<<<15 * KSPLIT, 256, 0, stream>>>(XT, M);
  k3a_cov<<<640, 256, 0, stream>>>(M, COV, MU);
  qform<<<256, 256, 0, stream>>>(COV, W1, 512, g1, A1);
  k3c_G<<<624, 256, 0, stream>>>(W1, A1, W2, G);
  qform<<<128, 256, 0, stream>>>(COV, G, 256, g2, A2);
  k3e_final<<<1, 256, 0, stream>>>(G, A2, MU, be2, bias, GW, CN);
  k5_out<<<512, 256, 0, stream>>>(Xi, Xv, emb1, XT, GW, CN, out);
}

// Round 7
// 337.528 us; speedup vs baseline: 1.1868x; 1.0174x over previous
//
#include <hip/hip_runtime.h>

#define B_ROWS 65536
#define F_FEAT 39
#define V_VOC  100000
#define D_PAD  640
#define BN_EPS 1e-5f
#define NPAIR  (39 * 32)

typedef __bf16 bf16x8 __attribute__((ext_vector_type(8)));
typedef float  f32x16 __attribute__((ext_vector_type(16)));

__device__ __forceinline__ unsigned short toBF(float x) {
  unsigned int u = __float_as_uint(x);
  u += 0x7fffu + ((u >> 16) & 1u);
  return (unsigned short)(u >> 16);
}

// ---------------- K0: transpose Xi/Xv to f-major; zero M; fill XT pad rows 624..639 ----------
__global__ __launch_bounds__(256) void k0_prep(
    const int* __restrict__ Xi, const float* __restrict__ Xv,
    int* __restrict__ XiT, float* __restrict__ XvT,
    float* __restrict__ M, unsigned short* __restrict__ XT) {
  for (int i = threadIdx.x; i < 800; i += 256)
    M[(size_t)blockIdx.x * 800 + i] = 0.f;

  const int b0 = blockIdx.x * 128;
  for (int u = threadIdx.x; u < 16 * 128; u += 256) {
    int m = 624 + (u >> 7), j = u & 127;
    XT[(size_t)m * B_ROWS + b0 + j] = (m == 624) ? (unsigned short)0x3f80 : (unsigned short)0;
  }

  __shared__ int   ti[128][41];
  __shared__ float tv[128][41];
  for (int u = threadIdx.x; u < 128 * 39; u += 256) {
    int r = u / 39, f = u - r * 39;
    ti[r][f] = Xi[(size_t)b0 * 39 + u];
    tv[r][f] = Xv[(size_t)b0 * 39 + u];
  }
  __syncthreads();
  for (int u = threadIdx.x; u < 39 * 128; u += 256) {
    int f = u >> 7, j = u & 127;
    XiT[(size_t)f * B_ROWS + b0 + j] = ti[j][f];
    XvT[(size_t)f * B_ROWS + b0 + j] = tv[j][f];
  }
}

// ---------------- K1f v2: persistent mega-blocks, f-major work order --------------------------
// 256 blocks x 1024 threads (1/CU, 16 waves). Block p processes work items idx = p, p+256, ...
// in f-major order (idx = f*32 + chunk). Active window at any instant ~256 items = 8 f's
// = 51 MB of emb2 -> L3-resident. (R6's 1248 small blocks were ALL co-resident -> no window.)
__global__ __launch_bounds__(1024) void k1f_gather(
    const int* __restrict__ XiT, const float* __restrict__ XvT,
    const float* __restrict__ emb2, unsigned short* __restrict__ XT) {
  __shared__ unsigned short xs[2][16][264];   // stripe transpose buffer, 2B pad vs conflicts

  const int seg = threadIdx.x & 3;        // 4-float segment of 16 dims
  const int bi  = threadIdx.x >> 2;       // 0..255: row within stripe
  const int dim = threadIdx.x >> 6;       // drain: 0..15
  const int prt = threadIdx.x & 63;       // drain: 64 x 8B = 512B per dim row

  for (int idx = blockIdx.x; idx < NPAIR; idx += gridDim.x) {
    const int f = idx >> 5;               // f-major: f changes every 32 items
    const int c = idx & 31;
    const int b0 = c * 2048;
    const float* ef = emb2 + (size_t)f * V_VOC * 16;
    const int*   xi = XiT + (size_t)f * B_ROWS + b0;
    const float* xv = XvT + (size_t)f * B_ROWS + b0;
    unsigned short* xtBase = XT + (size_t)(f * 16) * B_ROWS + b0;

    // software pipeline: idx 2 stripes ahead, gather 1 ahead
    int   idA = xi[bi],        idB = xi[256 + bi];
    float xvA = xv[bi],        xvB = xv[256 + bi];
    float4 v = *reinterpret_cast<const float4*>(ef + (size_t)idA * 16 + seg * 4);

    for (int s = 0; s < 8; ++s) {
      const float4 cur = v;
      const float  xvc = xvA;
      idA = idB; xvA = xvB;
      if (s + 2 < 8) {
        idB = xi[(s + 2) * 256 + bi];
        xvB = xv[(s + 2) * 256 + bi];
      }
      if (s + 1 < 8)
        v = *reinterpret_cast<const float4*>(ef + (size_t)idA * 16 + seg * 4);

      const int bf = s & 1;
      xs[bf][seg * 4 + 0][bi] = toBF(cur.x * xvc);
      xs[bf][seg * 4 + 1][bi] = toBF(cur.y * xvc);
      xs[bf][seg * 4 + 2][bi] = toBF(cur.z * xvc);
      xs[bf][seg * 4 + 3][bi] = toBF(cur.w * xvc);
      __syncthreads();
      // drain: 16 dims x 512B contiguous per dim (coalesced)
      uint2 w = *reinterpret_cast<const uint2*>(&xs[bf][dim][prt * 4]);
      *reinterpret_cast<uint2*>(xtBase + (size_t)dim * B_ROWS + s * 256 + prt * 4) = w;
    }
    __syncthreads();  // buffer reuse across pair iterations
  }
}

// ---------------- K2: M += Xt * Xt^T  (640x640, symmetric tiles ti<=tj), bf16 MFMA ----------
#define KSPLIT 32
__global__ __launch_bounds__(256) void k2_syrk(const unsigned short* __restrict__ XT,
                                               float* __restrict__ M) {
  const int p = blockIdx.x;
  const int xcd = p & 7;
  const int ks = ((p >> 3) / 15) * 8 + xcd;   // 0..31
  int pair = (p >> 3) % 15;
  int ti = 0;
  while (pair >= 5 - ti) { pair -= 5 - ti; ++ti; }
  const int tj = ti + pair;

  __shared__ unsigned short pa[128 * 64];
  __shared__ unsigned short pb[128 * 64];

  const int lane = threadIdx.x & 63, wid = threadIdx.x >> 6;
  const int wm = wid >> 1, wn = wid & 1;
  const int rl = lane & 31, hh = lane >> 5;

  f32x16 acc00, acc01, acc10, acc11;
#pragma unroll
  for (int i = 0; i < 16; ++i) { acc00[i] = 0.f; acc01[i] = 0.f; acc10[i] = 0.f; acc11[i] = 0.f; }

  const int krange = B_ROWS / KSPLIT;  // 2048
  const int kbase = ks * krange;

  for (int kt = 0; kt < krange; kt += 64) {
    const int k0 = kbase + kt;
#pragma unroll
    for (int g2 = 0; g2 < 4; ++g2) {
      const int g = threadIdx.x + g2 * 256;
      const int r = g >> 3, j = g & 7;
      uint4 va = *reinterpret_cast<const uint4*>(XT + (size_t)(ti * 128 + r) * B_ROWS + k0 + j * 8);
      *reinterpret_cast<uint4*>((char*)pa + r * 128 + ((j ^ (r & 7)) << 4)) = va;
      uint4 vb = *reinterpret_cast<const uint4*>(XT + (size_t)(tj * 128 + r) * B_ROWS + k0 + j * 8);
      *reinterpret_cast<uint4*>((char*)pb + r * 128 + ((j ^ (r & 7)) << 4)) = vb;
    }
    __syncthreads();
#pragma unroll
    for (int kc = 0; kc < 4; ++kc) {
      const int ra0 = wm * 64 + rl, ra1 = wm * 64 + 32 + rl;
      const int rb0 = wn * 64 + rl, rb1 = wn * 64 + 32 + rl;
      bf16x8 a0 = *reinterpret_cast<const bf16x8*>((char*)pa + ra0 * 128 + (((kc * 2 + hh) ^ (ra0 & 7)) << 4));
      bf16x8 a1 = *reinterpret_cast<const bf16x8*>((char*)pa + ra1 * 128 + (((kc * 2 + hh) ^ (ra1 & 7)) << 4));
      bf16x8 b0 = *reinterpret_cast<const bf16x8*>((char*)pb + rb0 * 128 + (((kc * 2 + hh) ^ (rb0 & 7)) << 4));
      bf16x8 b1 = *reinterpret_cast<const bf16x8*>((char*)pb + rb1 * 128 + (((kc * 2 + hh) ^ (rb1 & 7)) << 4));
      acc00 = __builtin_amdgcn_mfma_f32_32x32x16_bf16(a0, b0, acc00, 0, 0, 0);
      acc01 = __builtin_amdgcn_mfma_f32_32x32x16_bf16(a0, b1, acc01, 0, 0, 0);
      acc10 = __builtin_amdgcn_mfma_f32_32x32x16_bf16(a1, b0, acc10, 0, 0, 0);
      acc11 = __builtin_amdgcn_mfma_f32_32x32x16_bf16(a1, b1, acc11, 0, 0, 0);
    }
    __syncthreads();
  }

#pragma unroll
  for (int rr = 0; rr < 16; ++rr) {
    const int rloc = (rr & 3) + ((rr >> 2) << 3) + hh * 4;
    const int row0 = ti * 128 + wm * 64 + rloc;
    const int row1 = row0 + 32;
    const int col0 = tj * 128 + wn * 64 + rl;
    atomicAdd(&M[row0 * D_PAD + col0], acc00[rr]);
    atomicAdd(&M[row0 * D_PAD + col0 + 32], acc01[rr]);
    atomicAdd(&M[row1 * D_PAD + col0], acc10[rr]);
    atomicAdd(&M[row1 * D_PAD + col0 + 32], acc11[rr]);
  }
}

// ---------------- K3a: Cov + mu from M --------------------------------------------------------
__device__ __forceinline__ float fetchM(const float* M, int a, int b) {
  if ((a >> 7) > (b >> 7)) { int t = a; a = b; b = t; }
  return M[a * D_PAD + b];
}
__global__ void k3a_cov(const float* __restrict__ M, float* __restrict__ Cov,
                        float* __restrict__ mu) {
  const int i = blockIdx.x;
  const float inv = 1.f / 65536.f;
  const float mui = fetchM(M, 624, i) * inv;
  for (int j = threadIdx.x; j < D_PAD; j += 256) {
    float muj = fetchM(M, 624, j) * inv;
    Cov[i * D_PAD + j] = fetchM(M, i, j) * inv - mui * muj;
    if (i == 0) mu[j] = muj;
  }
}

// ---------------- qform: alpha[k] = g[k] * rsqrt( W[:,k]^T Cov W[:,k] + eps ), 2 k's/block -----
__global__ __launch_bounds__(256) void qform(const float* __restrict__ Cov,
                                             const float* __restrict__ W, const int ldw,
                                             const float* __restrict__ g,
                                             float* __restrict__ alpha) {
  const int k0 = blockIdx.x * 2;
  __shared__ float w0s[624], w1s[624];
  for (int i = threadIdx.x; i < 624; i += 256) {
    w0s[i] = W[(size_t)i * ldw + k0];
    w1s[i] = W[(size_t)i * ldw + k0 + 1];
  }
  __syncthreads();
  const int j0 = threadIdx.x, j1 = threadIdx.x + 256, j2 = threadIdx.x + 512;
  const bool v2 = (j2 < 624);
  const float wj00 = w0s[j0], wj01 = w0s[j1], wj02 = v2 ? w0s[j2] : 0.f;
  const float wj10 = w1s[j0], wj11 = w1s[j1], wj12 = v2 ? w1s[j2] : 0.f;
  float acc0 = 0.f, acc1 = 0.f;
  for (int i = 0; i < 624; ++i) {
    const float wi0 = w0s[i], wi1 = w1s[i];
    const float* row = Cov + i * D_PAD;
    const float c0 = row[j0], c1 = row[j1], c2 = v2 ? row[j2] : 0.f;
    acc0 += wi0 * (c0 * wj00 + c1 * wj01 + c2 * wj02);
    acc1 += wi1 * (c0 * wj10 + c1 * wj11 + c2 * wj12);
  }
#pragma unroll
  for (int off = 32; off > 0; off >>= 1) {
    acc0 += __shfl_down(acc0, off);
    acc1 += __shfl_down(acc1, off);
  }
  __shared__ float pr[2][4];
  const int lane = threadIdx.x & 63, wv = threadIdx.x >> 6;
  if (lane == 0) { pr[0][wv] = acc0; pr[1][wv] = acc1; }
  __syncthreads();
  if (threadIdx.x == 0) {
    float v0 = pr[0][0] + pr[0][1] + pr[0][2] + pr[0][3];
    float v1 = pr[1][0] + pr[1][1] + pr[1][2] + pr[1][3];
    alpha[k0]     = g[k0]     * rsqrtf(v0 + BN_EPS);
    alpha[k0 + 1] = g[k0 + 1] * rsqrtf(v1 + BN_EPS);
  }
}

// ---------------- K3c: G[i][j] = sum_k W1[i][k]*alpha1[k]*W2[k][j] ----------------------------
__global__ __launch_bounds__(256) void k3c_G(const float* __restrict__ W1,
                                             const float* __restrict__ alpha1,
                                             const float* __restrict__ W2,
                                             float* __restrict__ G) {
  const int i = blockIdx.x;
  __shared__ float a[512];
  for (int k = threadIdx.x; k < 512; k += 256)
    a[k] = W1[(size_t)i * 512 + k] * alpha1[k];
  __syncthreads();
  const int j = threadIdx.x;
  float acc = 0.f;
#pragma unroll 8
  for (int k = 0; k < 512; ++k) acc += a[k] * W2[(size_t)k * 256 + j];
  G[(size_t)i * 256 + j] = acc;
}

// ---------------- K3e: gw[i] = sum_j G[i][j]*alpha2[j];  consts = bias + sum(be2) - mu.gw -----
__global__ __launch_bounds__(256) void k3e_final(const float* __restrict__ G,
                                                 const float* __restrict__ alpha2,
                                                 const float* __restrict__ mu,
                                                 const float* __restrict__ be2,
                                                 const float* __restrict__ bias,
                                                 float* __restrict__ gw,
                                                 float* __restrict__ consts) {
  __shared__ float a2[256];
  __shared__ float gws[640];
  a2[threadIdx.x] = alpha2[threadIdx.x];
  __syncthreads();
  for (int i = threadIdx.x; i < 640; i += 256) {
    float acc = 0.f;
    if (i < 624) {
      const float* gr = G + (size_t)i * 256;
#pragma unroll 8
      for (int j = 0; j < 256; ++j) acc += gr[j] * a2[j];
    }
    gw[i] = acc;
    gws[i] = acc;
  }
  __syncthreads();
  float pm = 0.f;
  for (int i = threadIdx.x; i < 624; i += 256) pm += mu[i] * gws[i];
  float val = be2[threadIdx.x] - pm;
#pragma unroll
  for (int off = 32; off > 0; off >>= 1) val += __shfl_down(val, off);
  __shared__ float pr[4];
  const int lane = threadIdx.x & 63, wv = threadIdx.x >> 6;
  if (lane == 0) pr[wv] = val;
  __syncthreads();
  if (threadIdx.x == 0) consts[0] = bias[0] + pr[0] + pr[1] + pr[2] + pr[3];
}

// ---------------- K5: out[b] = consts + first(emb1) + gw.x + 0.5*(|sum|^2 - ssq) -------------
__global__ __launch_bounds__(256) void k5_out(const int* __restrict__ Xi,
                                              const float* __restrict__ Xv,
                                              const float* __restrict__ emb1,
                                              const unsigned short* __restrict__ XT,
                                              const float* __restrict__ gw,
                                              const float* __restrict__ consts,
                                              float* __restrict__ out) {
  const int b0 = blockIdx.x * 128;
  __shared__ int   si[128][40];
  __shared__ float sx[128][40];
  __shared__ float g[624];
  for (int m = threadIdx.x; m < 624; m += 256) g[m] = gw[m];
  for (int u = threadIdx.x; u < 128 * 39; u += 256) {
    int rr = u / 39, ff = u - rr * 39;
    si[rr][ff] = Xi[(size_t)b0 * 39 + u];
    sx[rr][ff] = Xv[(size_t)b0 * 39 + u];
  }
  __syncthreads();
  const int r = threadIdx.x >> 1, h = threadIdx.x & 1;
  const int b = b0 + r;
  const unsigned short* col = XT + b;

  float lin = 0.f, ssq = 0.f;
  float ps[16];
#pragma unroll
  for (int e = 0; e < 16; ++e) ps[e] = 0.f;

  const int m0 = h ? 320 : 0, m1 = h ? 624 : 320;
  for (int mo = m0; mo < m1; mo += 16) {
#pragma unroll
    for (int e = 0; e < 16; ++e) {
      const int m = mo + e;
      float x = __uint_as_float((unsigned int)col[(size_t)m * B_ROWS] << 16);
      lin += g[m] * x;
      ssq += x * x;
      ps[e] += x;
    }
  }
  const int fb = h ? 20 : 0, fe = h ? 39 : 20;
  for (int f = fb; f < fe; ++f)
    lin += emb1[(size_t)f * V_VOC + si[r][f]] * sx[r][f];

  float s2 = 0.f;
#pragma unroll
  for (int e = 0; e < 16; ++e) {
    float t = ps[e] + __shfl_xor(ps[e], 1);
    s2 += t * t;
  }
  // s2 is pair-total (identical on both lanes); lin/ssq are per-half partials.
  float tot = lin + 0.5f * (0.5f * s2 - ssq);
  tot += __shfl_xor(tot, 1);
  if (h == 0) out[b] = tot + consts[0];
}

// ---------------- host launch ----------------------------------------------------------------
extern "C" void kernel_launch(void* const* d_in, const int* in_sizes, int n_in,
                              void* d_out, int out_size, void* d_ws, size_t ws_size,
                              hipStream_t stream) {
  const int*   Xi   = (const int*)d_in[0];
  const float* Xv   = (const float*)d_in[1];
  const float* emb1 = (const float*)d_in[2];
  const float* emb2 = (const float*)d_in[3];
  const float* W1   = (const float*)d_in[4];
  const float* g1   = (const float*)d_in[6];
  const float* W2   = (const float*)d_in[8];
  const float* g2   = (const float*)d_in[10];
  const float* be2  = (const float*)d_in[11];
  const float* bias = (const float*)d_in[12];
  float* out = (float*)d_out;
  char* ws = (char*)d_ws;

  const size_t OFF_XT  = 0;
  const size_t OFF_M   = OFF_XT + (size_t)640 * 65536 * 2;   // 83.9 MB
  const size_t OFF_COV = OFF_M + (size_t)640 * 640 * 4;
  const size_t OFF_MU  = OFF_COV + (size_t)640 * 640 * 4;
  const size_t OFF_A1  = OFF_MU + 640 * 4;
  const size_t OFF_A2  = OFF_A1 + 512 * 4;
  const size_t OFF_G   = OFF_A2 + 256 * 4;
  const size_t OFF_GW  = OFF_G + (size_t)624 * 256 * 4;
  const size_t OFF_CN  = OFF_GW + 640 * 4;
  const size_t OFF_XIT = OFF_CN + 256;
  const size_t OFF_XVT = OFF_XIT + (size_t)39 * 65536 * 4;   // 10.2 MB

  unsigned short* XT = (unsigned short*)(ws + OFF_XT);
  float* M   = (float*)(ws + OFF_M);
  float* COV = (float*)(ws + OFF_COV);
  float* MU  = (float*)(ws + OFF_MU);
  float* A1  = (float*)(ws + OFF_A1);
  float* A2  = (float*)(ws + OFF_A2);
  float* G   = (float*)(ws + OFF_G);
  float* GW  = (float*)(ws + OFF_GW);
  float* CN  = (float*)(ws + OFF_CN);
  int*   XIT = (int*)(ws + OFF_XIT);
  float* XVT = (float*)(ws + OFF_XVT);

  k0_prep<<<512, 256, 0, stream>>>(Xi, Xv, XIT, XVT, M, XT);
  k1f_gather<<<256, 1024, 0, stream>>>(XIT, XVT, emb2, XT);
  k2_syrk<<<15 * KSPLIT, 256, 0, stream>>>(XT, M);
  k3a_cov<<<640, 256, 0, stream>>>(M, COV, MU);
  qform<<<256, 256, 0, stream>>>(COV, W1, 512, g1, A1);
  k3c_G<<<624, 256, 0, stream>>>(W1, A1, W2, G);
  qform<<<128, 256, 0, stream>>>(COV, G, 256, g2, A2);
  k3e_final<<<1, 256, 0, stream>>>(G, A2, MU, be2, bias, GW, CN);
  k5_out<<<512, 256, 0, stream>>>(Xi, Xv, emb1, XT, GW, CN, out);
}